// Round 10
// baseline (722.148 us; speedup 1.0000x reference)
//
#include <hip/hip_runtime.h>
#include <math.h>

#define DM 128            // d_model
#define WSTRIDE 16384     // 128x128 fp16 elements per packed weight matrix

typedef _Float16 f16x8 __attribute__((ext_vector_type(8)));
typedef _Float16 f16x4 __attribute__((ext_vector_type(4)));
typedef _Float16 f16x2 __attribute__((ext_vector_type(2)));
typedef float f32x4v __attribute__((ext_vector_type(4)));

// DPP quad-perm butterfly adds (4-lane reduce, no DS ops)
__device__ __forceinline__ float dpp_xor1_add(float x) {
    int r = __builtin_amdgcn_update_dpp(0, __builtin_bit_cast(int, x), 0xB1, 0xf, 0xf, true);
    return x + __builtin_bit_cast(float, r);
}
__device__ __forceinline__ float dpp_xor2_add(float x) {
    int r = __builtin_amdgcn_update_dpp(0, __builtin_bit_cast(int, x), 0x4E, 0xf, 0xf, true);
    return x + __builtin_bit_cast(float, r);
}
__device__ __forceinline__ uint32_t pkh(float x, float y) {
    f16x2 h = {(_Float16)x, (_Float16)y};
    return __builtin_bit_cast(uint32_t, h);
}

// ---------------- CSR build -------------------------------------------------
__global__ void count_kernel(const int* __restrict__ edst, int* __restrict__ deg, int E) {
    int e = blockIdx.x * blockDim.x + threadIdx.x;
    if (e < E) atomicAdd(&deg[edst[e]], 1);
}

__global__ void scan1_kernel(const int* __restrict__ in, int* __restrict__ outv,
                             int* __restrict__ bsums, int n) {
    __shared__ int s[256];
    int t = threadIdx.x;
    int i = blockIdx.x * 256 + t;
    int v = (i < n) ? in[i] : 0;
    s[t] = v;
    __syncthreads();
    for (int off = 1; off < 256; off <<= 1) {
        int x = (t >= off) ? s[t - off] : 0;
        __syncthreads();
        s[t] += x;
        __syncthreads();
    }
    if (i < n) outv[i] = s[t];
    if (t == 255) bsums[blockIdx.x] = s[255];
}

__global__ void scan2_kernel(int* __restrict__ bsums, int nb) {
    __shared__ int s[256];
    int t = threadIdx.x;
    int v = (t < nb) ? bsums[t] : 0;
    s[t] = v;
    __syncthreads();
    for (int off = 1; off < 256; off <<= 1) {
        int x = (t >= off) ? s[t - off] : 0;
        __syncthreads();
        s[t] += x;
        __syncthreads();
    }
    if (t < nb) bsums[t] = s[t];
}

// writes ptr[] and cursor[] (cursor = start offsets, consumed by scatter)
__global__ void scan3_kernel(const int* __restrict__ outv, const int* __restrict__ bsums,
                             int* __restrict__ ptr, int* __restrict__ cur, int n) {
    int i = blockIdx.x * 256 + threadIdx.x;
    if (i == 0) ptr[0] = 0;
    if (i < n) {
        int add = (blockIdx.x > 0) ? bsums[blockIdx.x - 1] : 0;
        int incl = outv[i] + add;
        ptr[i + 1] = incl;
        cur[i] = incl - ((i < n) ? (outv[i] - ((i & 255) ? outv[i] - outv[i] : 0)) : 0);
    }
}

// simpler: cursor init from ptr after scan3
__global__ void initcur_kernel(const int* __restrict__ ptr, int* __restrict__ cur, int n) {
    int i = blockIdx.x * blockDim.x + threadIdx.x;
    if (i < n) cur[i] = ptr[i];
}

__global__ void scatter_kernel(const int* __restrict__ esrc, const int* __restrict__ edst,
                               int* __restrict__ cur, int* __restrict__ out, int E) {
    int e = blockIdx.x * blockDim.x + threadIdx.x;
    if (e >= E) return;
    int pos = atomicAdd(&cur[edst[e]], 1);
    out[pos] = esrc[e];
}

// ---------------- W prepack: fp32 [128x128] -> fp16 MFMA-fragment order -----
// frag: ((kb*8+nb)*64 + lane)*8 + j <=> W[kb*32+(lane>>4)*8+j][nb*16+(lane&15)]
// matrices: 0..2 Wq, 3..5 Wk, 6..8 Wv, 9..11 Wo, 12 W1
__global__ void prepack_kernel(const float* __restrict__ Wq, const float* __restrict__ Wk,
                               const float* __restrict__ Wv, const float* __restrict__ Wo,
                               const float* __restrict__ W1, _Float16* __restrict__ W16) {
    int m = blockIdx.z;
    const float* W;
    if (m < 3)       W = Wq + (size_t)m * DM * DM;
    else if (m < 6)  W = Wk + (size_t)(m - 3) * DM * DM;
    else if (m < 9)  W = Wv + (size_t)(m - 6) * DM * DM;
    else if (m < 12) W = Wo + (size_t)(m - 9) * DM * DM;
    else             W = W1;
    int kb = blockIdx.x, nb = blockIdx.y, l = threadIdx.x;
    int kbase = kb * 32 + (l >> 4) * 8;
    int c = nb * 16 + (l & 15);
    f16x8 v;
#pragma unroll
    for (int j = 0; j < 8; j++) v[j] = (_Float16)W[(kbase + j) * DM + c];
    *reinterpret_cast<f16x8*>(W16 + (size_t)m * WSTRIDE + ((kb * 8 + nb) * 64 + l) * 8) = v;
}

// ---------------- tile GEMM (operand-swapped => row-major lane output) ------
// mfma(Wfrag, hfrag, acc): lane l holds OUT[row = rowb+(l&15)][col = nb*16+(l>>4)*4+i]
__device__ __forceinline__ void tile_gemm_T(const _Float16* __restrict__ sRow,
                                            const _Float16* __restrict__ W16, int lg, int l,
                                            f32x4v acc[8]) {
#pragma unroll
    for (int nb = 0; nb < 8; nb++) acc[nb] = (f32x4v){0.f, 0.f, 0.f, 0.f};
#pragma unroll
    for (int kb = 0; kb < 4; kb++) {
        f16x8 a = *reinterpret_cast<const f16x8*>(sRow + kb * 32 + lg * 8);
#pragma unroll
        for (int nb = 0; nb < 8; nb++) {
            f16x8 b = *reinterpret_cast<const f16x8*>(&W16[((kb * 8 + nb) * 64 + l) * 8]);
            acc[nb] = __builtin_amdgcn_mfma_f32_16x16x32_f16(b, a, acc[nb], 0, 0, 0);
        }
    }
}

__device__ __forceinline__ f16x4 pk4(const f32x4v a) {
    f16x4 h = {(_Float16)a[0], (_Float16)a[1], (_Float16)a[2], (_Float16)a[3]};
    return h;
}

// compute q,k,v from sRow (this lane's h row) and store packed fp16
__device__ __forceinline__ void qkv_store_T(const _Float16* __restrict__ sRow, int lr, int lg,
                                            int l, int rowb, int row0, int n,
                                            const _Float16* __restrict__ Wq16,
                                            const _Float16* __restrict__ Wk16,
                                            const _Float16* __restrict__ Wv16,
                                            _Float16* __restrict__ Qo,
                                            _Float16* __restrict__ KVo) {
    int r = row0 + rowb + lr;
    bool ok = (r < n);
    f32x4v acc[8];
    // Q
    tile_gemm_T(sRow, Wq16, lg, l, acc);
    if (ok) {
#pragma unroll
        for (int nb = 0; nb < 8; nb++)
            *reinterpret_cast<f16x4*>(Qo + (size_t)r * DM + nb * 16 + lg * 4) = pk4(acc[nb]);
    }
    // K
    tile_gemm_T(sRow, Wk16, lg, l, acc);
    if (ok) {
#pragma unroll
        for (int nb = 0; nb < 8; nb++)
            *reinterpret_cast<f16x4*>(KVo + (size_t)r * 256 + nb * 16 + lg * 4) = pk4(acc[nb]);
    }
    // V
    tile_gemm_T(sRow, Wv16, lg, l, acc);
    if (ok) {
#pragma unroll
        for (int nb = 0; nb < 8; nb++)
            *reinterpret_cast<f16x4*>(KVo + (size_t)r * 256 + 128 + nb * 16 + lg * 4) =
                pk4(acc[nb]);
    }
}

// ---------------- fused embed -> QKV ----------------------------------------
__global__ __launch_bounds__(256) void fused_embed_qkv_kernel(
    const float* __restrict__ X, const float* __restrict__ Seed,
    const float* __restrict__ Dg, const float* __restrict__ Cl,
    const float* __restrict__ Wseed, const float* __restrict__ Wdeg,
    const float* __restrict__ Wclu,
    const _Float16* __restrict__ Wq16, const _Float16* __restrict__ Wk16,
    const _Float16* __restrict__ Wv16,
    _Float16* __restrict__ Qo, _Float16* __restrict__ KVo, int n) {
    __shared__ _Float16 sH[64 * 136];
    int t = threadIdx.x;
    int row0 = blockIdx.x * 64;
    {
        int row = t >> 2, qt = t & 3;
        int gr = min(row0 + row, n - 1);
        float x = X[gr], sd = Seed[gr], dg = Dg[gr], cl = Cl[gr];
#pragma unroll
        for (int j = 0; j < 8; j++) {
            int c4 = qt * 32 + j * 4;
            float4 ws = *reinterpret_cast<const float4*>(Wseed + c4);
            float4 wd = *reinterpret_cast<const float4*>(Wdeg + c4);
            float4 wc = *reinterpret_cast<const float4*>(Wclu + c4);
            f16x4 h;
            h[0] = (_Float16)(x + sd * ws.x + dg * wd.x + cl * wc.x);
            h[1] = (_Float16)(x + sd * ws.y + dg * wd.y + cl * wc.y);
            h[2] = (_Float16)(x + sd * ws.z + dg * wd.z + cl * wc.z);
            h[3] = (_Float16)(x + sd * ws.w + dg * wd.w + cl * wc.w);
            *reinterpret_cast<f16x4*>(&sH[row * 136 + c4]) = h;
        }
    }
    __syncthreads();
    int w = t >> 6, l = t & 63;
    int lr = l & 15, lg = l >> 4;
    qkv_store_T(sH + (w * 16 + lr) * 136, lr, lg, l, w * 16, row0, n, Wq16, Wk16, Wv16, Qo, KVo);
}

// ---------------- fused Wo -> QKV -------------------------------------------
__global__ __launch_bounds__(256) void fused_wo_qkv_kernel(
    const _Float16* __restrict__ Ain, const _Float16* __restrict__ Wo16,
    const _Float16* __restrict__ Wq16, const _Float16* __restrict__ Wk16,
    const _Float16* __restrict__ Wv16,
    _Float16* __restrict__ Qo, _Float16* __restrict__ KVo, int n) {
    __shared__ _Float16 sA[64 * 136];
    __shared__ _Float16 sH[64 * 136];
    int t = threadIdx.x;
    int row0 = blockIdx.x * 64;
#pragma unroll
    for (int p = 0; p < 4; p++) {
        int f = p * 256 + t;
        int r = f >> 4, c8 = (f & 15) * 8;
        int gr = min(row0 + r, n - 1);
        *reinterpret_cast<uint4*>(&sA[r * 136 + c8]) =
            *reinterpret_cast<const uint4*>(Ain + (size_t)gr * DM + c8);
    }
    __syncthreads();
    int w = t >> 6, l = t & 63;
    int lr = l & 15, lg = l >> 4;
    int rowb = w * 16;
    f32x4v acc[8];
    tile_gemm_T(sA + (rowb + lr) * 136, Wo16, lg, l, acc);
    // spill h row (this lane owns row rowb+lr, cols nb*16+lg*4..+3) as b64 writes
#pragma unroll
    for (int nb = 0; nb < 8; nb++)
        *reinterpret_cast<f16x4*>(&sH[(rowb + lr) * 136 + nb * 16 + lg * 4]) = pk4(acc[nb]);
    __syncthreads();
    qkv_store_T(sH + (rowb + lr) * 136, lr, lg, l, rowb, row0, n, Wq16, Wk16, Wv16, Qo, KVo);
}

// ---------------- fused Wo -> MLP head --------------------------------------
__global__ __launch_bounds__(256) void fused_wo_mlp_kernel(
    const _Float16* __restrict__ Ain, const _Float16* __restrict__ Wo16,
    const _Float16* __restrict__ W116, const float* __restrict__ b1,
    const float* __restrict__ W2, const float* __restrict__ b2,
    float* __restrict__ out, int n) {
    __shared__ _Float16 sA[64 * 136];
    __shared__ _Float16 sH[64 * 136];
    int t = threadIdx.x;
    int row0 = blockIdx.x * 64;
#pragma unroll
    for (int p = 0; p < 4; p++) {
        int f = p * 256 + t;
        int r = f >> 4, c8 = (f & 15) * 8;
        int gr = min(row0 + r, n - 1);
        *reinterpret_cast<uint4*>(&sA[r * 136 + c8]) =
            *reinterpret_cast<const uint4*>(Ain + (size_t)gr * DM + c8);
    }
    __syncthreads();
    int w = t >> 6, l = t & 63;
    int lr = l & 15, lg = l >> 4;
    int rowb = w * 16;
    f32x4v acc[8];
    tile_gemm_T(sA + (rowb + lr) * 136, Wo16, lg, l, acc);
#pragma unroll
    for (int nb = 0; nb < 8; nb++)
        *reinterpret_cast<f16x4*>(&sH[(rowb + lr) * 136 + nb * 16 + lg * 4]) = pk4(acc[nb]);
    __syncthreads();
    tile_gemm_T(sH + (rowb + lr) * 136, W116, lg, l, acc);
    // lane holds row rowb+lr, cols nb*16+lg*4+i ; reduce over cols
    float part = 0.f;
#pragma unroll
    for (int nb = 0; nb < 8; nb++) {
#pragma unroll
        for (int i = 0; i < 4; i++) {
            int c = nb * 16 + lg * 4 + i;
            part += fmaxf(acc[nb][i] + b1[c], 0.f) * W2[c];
        }
    }
    part += __shfl_xor(part, 16, 64);
    part += __shfl_xor(part, 32, 64);
    int r = row0 + rowb + lr;
    if (lg == 0 && r < n) out[r] = part + b2[0];
}

// ---------------- attention: wave = dst node, 4 edges/APROC, depth-4 --------
// lane: quarter q4 = lane>>4 (one edge of the 4), w = lane&15 holds dims [8w,8w+8).
// Head = w>>2 -> reduce over 4 lanes via DPP quad-perm. exp2 online softmax,
// defer-max THR=8. KV row: [128 f16 K][128 f16 V].
__global__ __launch_bounds__(256) void attn_kernel(const _Float16* __restrict__ Q,
                                                   const uint32_t* __restrict__ KV,
                                                   const int* __restrict__ ptr,
                                                   const int* __restrict__ esrc,
                                                   _Float16* __restrict__ AGG, int n) {
    int wv = threadIdx.x >> 6;
    int lane = threadIdx.x & 63;
    int node = blockIdx.x * 4 + wv;
    if (node >= n) return;
    int e0 = ptr[node], e1 = ptr[node + 1];
    int q4 = lane >> 4;
    int w = lane & 15;
    _Float16* outbase = AGG + (size_t)node * DM + 8 * w;
    if (e0 >= e1) {
        if (lane < 16) *reinterpret_cast<uint4*>(outbase) = make_uint4(0, 0, 0, 0);
        return;
    }
    const float scale = 0.17677669529663687f * 1.4426950408889634f;
    uint4 qv = *reinterpret_cast<const uint4*>(Q + (size_t)node * DM + 8 * w);
    f16x2 qh0 = __builtin_bit_cast(f16x2, qv.x);
    f16x2 qh1 = __builtin_bit_cast(f16x2, qv.y);
    f16x2 qh2 = __builtin_bit_cast(f16x2, qv.z);
    f16x2 qh3 = __builtin_bit_cast(f16x2, qv.w);

    float m = -1e30f, s = 0.f;
    float a0 = 0.f, a1 = 0.f, a2 = 0.f, a3 = 0.f, a4 = 0.f, a5 = 0.f, a6 = 0.f, a7 = 0.f;

    int last = e1 - 1;
    int S = (e1 - e0 + 3) >> 2;          // APROC sub-iters
    int loops = (S + 3) >> 2;            // 4 sub-iters per loop

    const uint32_t* kvw = KV + w * 4;

    uint4 k0, v0, k1, v1, k2, v2, k3, v3;
    {
        const uint32_t* r0 = kvw + (size_t)esrc[min(e0 + q4, last)] * 128;
        k0 = *reinterpret_cast<const uint4*>(r0);
        v0 = *reinterpret_cast<const uint4*>(r0 + 64);
        const uint32_t* r1 = kvw + (size_t)esrc[min(e0 + 4 + q4, last)] * 128;
        k1 = *reinterpret_cast<const uint4*>(r1);
        v1 = *reinterpret_cast<const uint4*>(r1 + 64);
        const uint32_t* r2 = kvw + (size_t)esrc[min(e0 + 8 + q4, last)] * 128;
        k2 = *reinterpret_cast<const uint4*>(r2);
        v2 = *reinterpret_cast<const uint4*>(r2 + 64);
        const uint32_t* r3 = kvw + (size_t)esrc[min(e0 + 12 + q4, last)] * 128;
        k3 = *reinterpret_cast<const uint4*>(r3);
        v3 = *reinterpret_cast<const uint4*>(r3 + 64);
    }
    int idxn = esrc[min(e0 + 16 + q4, last)];

#define APROC(kc, vc, bidx)                                                            \
    {                                                                                  \
        float p = __builtin_amdgcn_fdot2(qh0, __builtin_bit_cast(f16x2, (kc).x), 0.f, false); \
        p = __builtin_amdgcn_fdot2(qh1, __builtin_bit_cast(f16x2, (kc).y), p, false);  \
        p = __builtin_amdgcn_fdot2(qh2, __builtin_bit_cast(f16x2, (kc).z), p, false);  \
        p = __builtin_amdgcn_fdot2(qh3, __builtin_bit_cast(f16x2, (kc).w), p, false);  \
        p = dpp_xor1_add(p);                                                           \
        p = dpp_xor2_add(p);                                                           \
        p *= scale;                                                                    \
        p = ((bidx) < e1) ? p : -3.0e38f;                                              \
        float diff = p - m;                                                            \
        if (__any(diff > 8.f)) {                                                       \
            float mn = fmaxf(m, p);                                                    \
            float dd = exp2f(m - mn);                                                  \
            s *= dd;                                                                   \
            a0 *= dd; a1 *= dd; a2 *= dd; a3 *= dd;                                    \
            a4 *= dd; a5 *= dd; a6 *= dd; a7 *= dd;                                    \
            m = mn;                                                                    \
            diff = p - m;                                                              \
        }                                                                              \
        float wg = exp2f(diff);                                                        \
        s += wg;                                                                       \
        f16x2 vh0 = __builtin_bit_cast(f16x2, (vc).x);                                 \
        f16x2 vh1 = __builtin_bit_cast(f16x2, (vc).y);                                 \
        f16x2 vh2 = __builtin_bit_cast(f16x2, (vc).z);                                 \
        f16x2 vh3 = __builtin_bit_cast(f16x2, (vc).w);                                 \
        a0 += wg * (float)vh0[0]; a1 += wg * (float)vh0[1];                            \
        a2 += wg * (float)vh1[0]; a3 += wg * (float)vh1[1];                            \
        a4 += wg * (float)vh2[0]; a5 += wg * (float)vh2[1];                            \
        a6 += wg * (float)vh3[0]; a7 += wg * (float)vh3[1];                            \
    }

#define SUBSTEP(kx, vx)                                                                \
    {                                                                                  \
        uint4 kc = kx, vc = vx;                                                        \
        const uint32_t* r = kvw + (size_t)idxn * 128;                                  \
        kx = *reinterpret_cast<const uint4*>(r);                                       \
        vx = *reinterpret_cast<const uint4*>(r + 64);                                  \
        idxn = esrc[min(b + 20, last)];                                                \
        APROC(kc, vc, b);                                                              \
        b += 4;                                                                        \
    }

    int b = e0 + q4;
    for (int it = 0; it < loops; it++) {
        SUBSTEP(k0, v0);
        SUBSTEP(k1, v1);
        SUBSTEP(k2, v2);
        SUBSTEP(k3, v3);
    }
#undef SUBSTEP
#undef APROC

    // merge the 4 quarter-chains
#pragma unroll
    for (int off = 16; off <= 32; off <<= 1) {
        float m2 = __shfl_xor(m, off, 64);
        float s2 = __shfl_xor(s, off, 64);
        float b0 = __shfl_xor(a0, off, 64), b1 = __shfl_xor(a1, off, 64);
        float b2 = __shfl_xor(a2, off, 64), b3 = __shfl_xor(a3, off, 64);
        float b4 = __shfl_xor(a4, off, 64), b5 = __shfl_xor(a5, off, 64);
        float b6 = __shfl_xor(a6, off, 64), b7 = __shfl_xor(a7, off, 64);
        float mF = fmaxf(m, m2);
        float d1 = exp2f(m - mF), d2 = exp2f(m2 - mF);
        s = s * d1 + s2 * d2;
        a0 = a0 * d1 + b0 * d2; a1 = a1 * d1 + b1 * d2;
        a2 = a2 * d1 + b2 * d2; a3 = a3 * d1 + b3 * d2;
        a4 = a4 * d1 + b4 * d2; a5 = a5 * d1 + b5 * d2;
        a6 = a6 * d1 + b6 * d2; a7 = a7 * d1 + b7 * d2;
        m = mF;
    }

    float inv = 1.f / (s + 1e-9f);
    if (lane < 16) {
        uint4 o;
        o.x = pkh(a0 * inv, a1 * inv);
        o.y = pkh(a2 * inv, a3 * inv);
        o.z = pkh(a4 * inv, a5 * inv);
        o.w = pkh(a6 * inv, a7 * inv);
        *reinterpret_cast<uint4*>(outbase) = o;
    }
}

// ---------------------------------------------------------------------------
extern "C" void kernel_launch(void* const* d_in, const int* in_sizes, int n_in,
                              void* d_out, int out_size, void* d_ws, size_t ws_size,
                              hipStream_t stream) {
    const float* X    = (const float*)d_in[0];
    const float* Seed = (const float*)d_in[1];
    const float* Dg   = (const float*)d_in[2];
    const float* Cl   = (const float*)d_in[3];
    const int* esrc   = (const int*)d_in[4];
    const int* edst   = (const int*)d_in[5];
    const float* Wseed = (const float*)d_in[6];
    const float* Wdeg  = (const float*)d_in[7];
    const float* Wclu  = (const float*)d_in[8];
    const float* Wq = (const float*)d_in[9];
    const float* Wk = (const float*)d_in[10];
    const float* Wv = (const float*)d_in[11];
    const float* Wo = (const float*)d_in[12];
    const float* W1 = (const float*)d_in[13];
    const float* b1 = (const float*)d_in[14];
    const float* W2 = (const float*)d_in[15];
    const float* b2 = (const float*)d_in[16];
    float* out = (float*)d_out;

    int n = in_sizes[0];
    int E = in_sizes[4];

    char* p = (char*)d_ws;
    auto alloc = [&](size_t bytes) {
        void* r = (void*)p;
        p += (bytes + 255) & ~(size_t)255;
        return r;
    };
    _Float16* qbuf = (_Float16*)alloc((size_t)n * DM * 2);             // q fp16
    _Float16* abuf = (_Float16*)alloc((size_t)n * DM * 2);             // agg fp16
    unsigned short* kvbuf = (unsigned short*)alloc((size_t)n * 256 * 2);  // fp16 K|V
    _Float16* W16 = (_Float16*)alloc((size_t)13 * WSTRIDE * 2);        // packed weights
    int* deg    = (int*)alloc((size_t)n * 4);
    int* ptr    = (int*)alloc((size_t)(n + 1) * 4);
    int* ptrtmp = (int*)alloc((size_t)n * 4);
    int* bsums  = (int*)alloc(1024);
    int* cur    = (int*)alloc((size_t)n * 4);
    int* esrcs  = (int*)alloc((size_t)E * 4);
    (void)ws_size; (void)n_in; (void)out_size;

    hipMemsetAsync(deg, 0, (size_t)n * 4, stream);

    int nb = (n + 255) / 256;
    count_kernel<<<(E + 255) / 256, 256, 0, stream>>>(edst, deg, E);
    scan1_kernel<<<nb, 256, 0, stream>>>(deg, ptrtmp, bsums, n);
    scan2_kernel<<<1, 256, 0, stream>>>(bsums, nb);
    scan3_kernel<<<nb, 256, 0, stream>>>(ptrtmp, bsums, ptr, cur, n);
    initcur_kernel<<<nb, 256, 0, stream>>>(ptr, cur, n);
    scatter_kernel<<<(E + 255) / 256, 256, 0, stream>>>(esrc, edst, cur, esrcs, E);

    prepack_kernel<<<dim3(4, 8, 13), 64, 0, stream>>>(Wq, Wk, Wv, Wo, W1, W16);

    int ggrid = (n + 63) / 64;
    int agrid = (n + 3) / 4;
    const uint32_t* KVc = (const uint32_t*)kvbuf;

    // layer 1: embed fused into QKV
    fused_embed_qkv_kernel<<<ggrid, 256, 0, stream>>>(
        X, Seed, Dg, Cl, Wseed, Wdeg, Wclu,
        W16 + (size_t)0 * WSTRIDE, W16 + (size_t)3 * WSTRIDE, W16 + (size_t)6 * WSTRIDE,
        qbuf, (_Float16*)kvbuf, n);
    attn_kernel<<<agrid, 256, 0, stream>>>(qbuf, KVc, ptr, esrcs, abuf, n);
    // layers 2,3: Wo fused into next QKV
    for (int i = 0; i < 2; i++) {
        fused_wo_qkv_kernel<<<ggrid, 256, 0, stream>>>(
            abuf, W16 + (size_t)(9 + i) * WSTRIDE,
            W16 + (size_t)(1 + i) * WSTRIDE, W16 + (size_t)(4 + i) * WSTRIDE,
            W16 + (size_t)(7 + i) * WSTRIDE, qbuf, (_Float16*)kvbuf, n);
        attn_kernel<<<agrid, 256, 0, stream>>>(qbuf, KVc, ptr, esrcs, abuf, n);
    }
    // final: Wo3 fused with MLP head
    fused_wo_mlp_kernel<<<ggrid, 256, 0, stream>>>(
        abuf, W16 + (size_t)11 * WSTRIDE, W16 + (size_t)12 * WSTRIDE, b1, W2, b2, out, n);
}